// Round 15
// baseline (865.300 us; speedup 1.0000x reference)
//
#include <hip/hip_runtime.h>
#include <math.h>

#define BB  256
#define TT  2048
#define VV  64
#define DD  50
#define HH  50
#define HIDN 100

typedef float f32x2 __attribute__((ext_vector_type(2)));

// [tok][j] = seqFMA_d(embed[tok][d]*Wx[d][j]) + b_rnn[j]; cols 50..63 = 0.
__device__ float g_emWxb[VV * 64];
// [cg][i][k] = W1[i][4*cg+k] (i<50, else 0): packed pairs for v_pk_fma_f32.
__device__ float g_W1P[25 * 64 * 4];

// ---------------------------------------------------------------------------
// XLA/Eigen fast-tanh, FMA-contracted Horner. BIT-EXACT with the reference
// trajectory (R6-R14 pass, absmax 0.015625). Do not touch.
// ---------------------------------------------------------------------------
__device__ __forceinline__ float xla_tanhf_fma(float x) {
#pragma clang fp contract(off)
  float ax = fabsf(x);
  float cx = fminf(fmaxf(x, -7.90531110763549805f), 7.90531110763549805f);
  float x2 = cx * cx;
  float p = -2.76076847742355e-16f;
  p = fmaf(x2, p, 2.00018790482477e-13f);
  p = fmaf(x2, p, -8.60467152213735e-11f);
  p = fmaf(x2, p, 5.12229709037114e-08f);
  p = fmaf(x2, p, 1.48572235717979e-05f);
  p = fmaf(x2, p, 6.37261928875436e-04f);
  p = fmaf(x2, p, 4.89352455891786e-03f);
  p = cx * p;
  float q = 1.19825839466702e-06f;
  q = fmaf(x2, q, 1.18534705686654e-04f);
  q = fmaf(x2, q, 2.26843463243900e-03f);
  q = fmaf(x2, q, 4.89352518554385e-03f);
  float r = p / q;
  return (ax < 0.0004f) ? x : r;
}

// ---------------------------------------------------------------------------
// K1: xp table, Eigen-gemm bit-emulation (unchanged from passing R6).
// ---------------------------------------------------------------------------
__global__ __launch_bounds__(256) void prep_kernel(
    const float* __restrict__ embed, const float* __restrict__ Wx,
    const float* __restrict__ b_rnn) {
#pragma clang fp contract(off)
  int o = blockIdx.x * 256 + threadIdx.x;
  if (o >= VV * 64) return;
  int v = o >> 6, j = o & 63;
  float val = 0.f;
  if (j < HH) {
    float s = 0.f;
    for (int d = 0; d < DD; ++d)
      s = fmaf(embed[v * DD + d], Wx[d * HH + j], s);
    val = s + b_rnn[j];
  }
  g_emWxb[o] = val;
}

// K1b: W1 -> packed [cg][i][4] layout (pure data movement, bit-exact).
__global__ __launch_bounds__(256) void prep2_kernel(const float* __restrict__ W1) {
  int o = blockIdx.x * 256 + threadIdx.x;
  if (o >= 25 * 64 * 4) return;
  int cg = o >> 8, i = (o >> 2) & 63, k = o & 3;
  g_W1P[o] = (i < HH) ? W1[i * HIDN + cg * 4 + k] : 0.f;
}

// ---------------------------------------------------------------------------
// K2: recurrence — FROZEN at R11/R14 (541us, 634cyc/step). The serial chain
// (ds write->read ~130 + 50-dep-FMA 200 + tanh w/ IEEE div ~120) is the
// structural floor for this decomposition; R14's load-stagger was an exact
// null (compiler already fine-schedules lgkmcnt). Bit-critical: 50x fmaf
// ascending i, single acc; pre = xp + acc; xla_tanhf_fma. Chaos gain ~1.3e7.
// ---------------------------------------------------------------------------
__global__ __launch_bounds__(64) void rnn_kernel(
    const int* __restrict__ inputs, const float* __restrict__ Wh,
    float* hs) {
#pragma clang fp contract(off)
  const int b = blockIdx.x;
  const int lane = threadIdx.x;

  __shared__ __align__(16) float emw[VV * 64];  // 16 KB
  __shared__ int toks[TT];                      // 8 KB
  __shared__ __align__(16) float hshare[64];

  for (int o = lane; o < VV * 64; o += 64) emw[o] = g_emWxb[o];
  const int* rowp = inputs + (size_t)b * TT;
  for (int t = lane; t < TT; t += 64) toks[t] = rowp[t];

  float whcol[HH];
#pragma unroll
  for (int i = 0; i < HH; ++i)
    whcol[i] = (lane < HH) ? Wh[i * HH + lane] : 0.f;

  hshare[lane] = 0.f;   // h(-1) = 0
  __syncthreads();      // once (staging)

  float* outp = hs + (size_t)b * TT * 64;
  float h = 0.f;
  float xp = emw[toks[0] * 64 + lane];
  const float4* hp = reinterpret_cast<const float4*>(hshare);

#define FMA4(v, base)                         \
  acc = fmaf((v).x, whcol[(base) + 0], acc);  \
  acc = fmaf((v).y, whcol[(base) + 1], acc);  \
  acc = fmaf((v).z, whcol[(base) + 2], acc);  \
  acc = fmaf((v).w, whcol[(base) + 3], acc);

  for (int t = 0; t < TT; ++t) {
    float4 h0 = hp[0];
    float4 h1 = hp[1];
    float4 h2 = hp[2];
    float4 h3 = hp[3];
    float acc = 0.f;
    FMA4(h0, 0)  float4 h4 = hp[4];
    FMA4(h1, 4)  float4 h5 = hp[5];
    FMA4(h2, 8)  float4 h6 = hp[6];
    FMA4(h3, 12) float4 h7 = hp[7];
    FMA4(h4, 16) float4 h8 = hp[8];
    FMA4(h5, 20) float4 h9 = hp[9];
    FMA4(h6, 24) float4 h10 = hp[10];
    FMA4(h7, 28) float4 h11 = hp[11];
    FMA4(h8, 32) float4 h12 = hp[12];
    FMA4(h9, 36)
    FMA4(h10, 40)
    FMA4(h11, 44)
    acc = fmaf(h12.x, whcol[48], acc);
    acc = fmaf(h12.y, whcol[49], acc);
    float pre = xp + acc;

    int tn = toks[(t + 1 < TT) ? (t + 1) : (TT - 1)];
    float xpn = emw[tn * 64 + lane];

    h = xla_tanhf_fma(pre);
    hshare[lane] = h;                  // publish (same-wave RAW, no barrier)
    outp[(size_t)t * 64 + lane] = h;   // coalesced fire-and-forget
    xp = xpn;
  }
#undef FMA4
}

// ---------------------------------------------------------------------------
// K3: MLP head, PACKED-f32 (v_pk_fma_f32): one thread per (b,t) row.
// Packing is across INDEPENDENT chains only — a-chains (a0,a1)/(a2,a3) pairs,
// logit (jj,jj+1) pairs — each element's fmaf sequence keeps the exact R6
// order => bit-identical (absmax must stay exactly 0.015625). Ops per
// c-group: 456 scalar -> ~232 packed, halving VALU issue time.
// __builtin_elementwise_fma on float2 -> v_pk_fma_f32 on gfx950 (if the
// compiler scalarizes, perf is neutral, bits unchanged — zero-risk).
// hs/out may alias -> NO restrict; thread r reads row r before writing it.
// ---------------------------------------------------------------------------
__global__ __launch_bounds__(256) void head_kernel(
    const float* hs, const float* __restrict__ b1,
    const float* __restrict__ W2, const float* __restrict__ b2,
    float* out) {
#pragma clang fp contract(off)
  const int r = blockIdx.x * 256 + threadIdx.x;  // 0 .. B*T-1
  const float* hrow = hs + (size_t)r * 64;

  float h[52];
#pragma unroll
  for (int q = 0; q < 13; ++q) {     // hrow is 256B-aligned
    float4 v = *reinterpret_cast<const float4*>(hrow + 4 * q);
    h[4 * q + 0] = v.x;
    h[4 * q + 1] = v.y;
    h[4 * q + 2] = v.z;
    h[4 * q + 3] = v.w;
  }

  f32x2 logit2[32];
  const f32x2* b2p = reinterpret_cast<const f32x2*>(b2);
#pragma unroll
  for (int k = 0; k < 32; ++k) logit2[k] = b2p[k];

  for (int cg = 0; cg < 25; ++cg) {   // c = 4*cg
    const f32x2* w1p = reinterpret_cast<const f32x2*>(g_W1P + cg * 256);
    f32x2 A01 = {0.f, 0.f}, A23 = {0.f, 0.f};
#pragma unroll
    for (int i = 0; i < HH; ++i) {    // per-chain ascending i = R6 order
      f32x2 hb = {h[i], h[i]};
      A01 = __builtin_elementwise_fma(hb, w1p[2 * i + 0], A01);
      A23 = __builtin_elementwise_fma(hb, w1p[2 * i + 1], A23);
    }
    const int c = cg * 4;
    float a0 = A01.x + b1[c + 0]; a0 = fmaxf(a0, 0.f);
    float a1 = A01.y + b1[c + 1]; a1 = fmaxf(a1, 0.f);
    float a2 = A23.x + b1[c + 2]; a2 = fmaxf(a2, 0.f);
    float a3 = A23.y + b1[c + 3]; a3 = fmaxf(a3, 0.f);
    f32x2 A0 = {a0, a0}, A1 = {a1, a1}, A2 = {a2, a2}, A3 = {a3, a3};
    const f32x2* v0 = reinterpret_cast<const f32x2*>(W2 + (c + 0) * VV);
    const f32x2* v1 = reinterpret_cast<const f32x2*>(W2 + (c + 1) * VV);
    const f32x2* v2 = reinterpret_cast<const f32x2*>(W2 + (c + 2) * VV);
    const f32x2* v3 = reinterpret_cast<const f32x2*>(W2 + (c + 3) * VV);
#pragma unroll
    for (int k = 0; k < 32; ++k) {    // per-element: a0,a1,a2,a3 then next c-group = R6 order
      f32x2 L = logit2[k];
      L = __builtin_elementwise_fma(A0, v0[k], L);
      L = __builtin_elementwise_fma(A1, v1[k], L);
      L = __builtin_elementwise_fma(A2, v2[k], L);
      L = __builtin_elementwise_fma(A3, v3[k], L);
      logit2[k] = L;
    }
  }

  float* orow = out + (size_t)r * 64;
#pragma unroll
  for (int q = 0; q < 16; ++q) {
    float4 v;
    v.x = logit2[2 * q + 0].x;
    v.y = logit2[2 * q + 0].y;
    v.z = logit2[2 * q + 1].x;
    v.w = logit2[2 * q + 1].y;
    *reinterpret_cast<float4*>(orow + 4 * q) = v;
  }
}

// ---------------------------------------------------------------------------
extern "C" void kernel_launch(void* const* d_in, const int* in_sizes, int n_in,
                              void* d_out, int out_size, void* d_ws, size_t ws_size,
                              hipStream_t stream) {
  // Map inputs by element-count signature (dict order breaks the Wx/Wh tie).
  const void* p[9] = {nullptr};
  const int want[9] = {BB * TT, VV * DD, DD * HH, HH * HH, HH,
                       HH * HIDN, HIDN, HIDN * VV, VV};
  bool used[32] = {false};
  for (int k = 0; k < 9; ++k)
    for (int i = 0; i < n_in && i < 32; ++i)
      if (!used[i] && in_sizes[i] == want[k]) { p[k] = d_in[i]; used[i] = true; break; }

  const int*   inputs = (const int*)  p[0];
  const float* embed  = (const float*)p[1];
  const float* Wx     = (const float*)p[2];
  const float* Wh     = (const float*)p[3];
  const float* b_rnn  = (const float*)p[4];
  const float* W1     = (const float*)p[5];
  const float* b1     = (const float*)p[6];
  const float* W2     = (const float*)p[7];
  const float* b2     = (const float*)p[8];

  float* out = (float*)d_out;
  float* hs = (ws_size >= (size_t)(BB * TT * 64) * sizeof(float))
                  ? (float*)d_ws : out;

  prep_kernel<<<(VV * 64 + 255) / 256, 256, 0, stream>>>(embed, Wx, b_rnn);
  prep2_kernel<<<(25 * 64 * 4 + 255) / 256, 256, 0, stream>>>(W1);
  rnn_kernel<<<BB, 64, 0, stream>>>(inputs, Wh, hs);
  head_kernel<<<(BB * TT) / 256, 256, 0, stream>>>(hs, b1, W2, b2, out);
}